// Round 10
// baseline (618.251 us; speedup 1.0000x reference)
//
#include <hip/hip_runtime.h>
#include <hip/hip_bf16.h>

#define NN 50000
#define EE 800000
#define EP 850000   // EE + NN self-loops
#define DD 128
#define NB 196      // ceil(NN/256)

#define NBUCK 196        // dst buckets: b = d >> 8 (d_max 49999 -> 195)
#define BCAP 8192        // slots per bucket (mean ~4350, 1.9x headroom)
#define E_PER_BLK 4096   // edges per binpass1 block (16/thread)
#define GEMM_BLKS 782    // ceil(NN/64)
#define BP1_BLKS ((EP + E_PER_BLK - 1)/E_PER_BLK)   // 208

typedef __attribute__((ext_vector_type(8))) short short8;
typedef __attribute__((ext_vector_type(4))) float f32x4;

__device__ __forceinline__ float bfu(unsigned short u){ return __uint_as_float(((unsigned)u)<<16); }
__device__ __forceinline__ unsigned short f2bs(float x){
  __hip_bfloat16 h = __float2bfloat16(x);
  union { __hip_bfloat16 h; unsigned short u; } cv; cv.h = h; return cv.u;
}

// ---------------- prep: zero bucket cursors (block 0) + pack W tiles (blocks 0..23)
// ---------------- + W@a fragments (blocks 24..119) --------------------------
__global__ void __launch_bounds__(256) prep_kernel(
    const float* __restrict__ W0, const float* __restrict__ as0, const float* __restrict__ ad0,
    const float* __restrict__ W1, const float* __restrict__ as1, const float* __restrict__ ad1,
    const float* __restrict__ W2, const float* __restrict__ as2, const float* __restrict__ ad2,
    unsigned short* __restrict__ Wmf, int* __restrict__ bcur)
{
  const int tid = threadIdx.x;
  if (blockIdx.x == 0 && tid < NBUCK) bcur[tid] = 0;
  if (blockIdx.x < 24){
    // W reformat, tiles 0..31
    const int L = blockIdx.x >> 3, seg = blockIdx.x & 7;
    const float* W = (L == 0) ? W0 : (L == 1) ? W1 : W2;
    int idx = seg*256 + tid;                  // 0..2047
    int t = idx >> 6, lane = idx & 63;        // t 0..31
    int c = t >> 2, kb = t & 3;
    int m = lane & 15, quad = lane >> 4;
    unsigned short out[8];
    #pragma unroll
    for (int j = 0; j < 8; j++){
      int k = kb*32 + quad*8 + j;
      out[j] = f2bs(W[(size_t)k*DD + c*16 + m]);
    }
    *(uint4*)&Wmf[(((size_t)L*36 + t)*64 + lane)*8] = *(const uint4*)out;
  } else if (blockIdx.x < 120){
    // W@a_src / W@a_dst -> tile 8; one wave per (layer,k)
    const int q = blockIdx.x - 24;
    const int wIdx = q*4 + (tid >> 6);        // 0..383
    const int L = wIdx >> 7, k = wIdx & 127;
    const float *W, *as, *ad; int H;
    if (L == 0){ W = W0; as = as0; ad = ad0; H = 8; }
    else if (L == 1){ W = W1; as = as1; ad = ad1; H = 8; }
    else { W = W2; as = as2; ad = ad2; H = 1; }
    const int lane = tid & 63;
    const int c0 = lane*2;
    float w0 = W[(size_t)k*DD + c0];
    float w1 = W[(size_t)k*DD + c0 + 1];
    float ps = w0*as[c0] + w1*as[c0+1];
    float pd = w0*ad[c0] + w1*ad[c0+1];
    if (H == 8){
      #pragma unroll
      for (int off = 1; off <= 4; off <<= 1){   // reduce within 8-lane head groups
        ps += __shfl_xor(ps, off, 64);
        pd += __shfl_xor(pd, off, 64);
      }
    } else {
      #pragma unroll
      for (int off = 1; off <= 32; off <<= 1){  // full-wave reduce
        ps += __shfl_xor(ps, off, 64);
        pd += __shfl_xor(pd, off, 64);
      }
    }
    int srcLane = (lane < 8) ? lane*8 : (lane < 16 ? (lane-8)*8 : 0);
    float vs = __shfl(ps, srcLane, 64);
    float vd = __shfl(pd, srcLane, 64);
    float myv;
    if (H == 8) myv = (lane < 8) ? vs : (lane < 16 ? vd : 0.f);
    else        myv = (lane == 0) ? ps : (lane == 1 ? pd : 0.f);
    const int kb = k >> 5, quad = (k >> 3) & 3, j = k & 7;
    if (lane < 16)
      Wmf[(((size_t)L*36 + 32 + kb)*64 + quad*16 + lane)*8 + j] = f2bs(myv);
  }
}

// ---------------- binpass1 body (fused into layer-0 launch, blocks first) ----------------
__device__ __forceinline__ void bp1_body(int bid, const int* __restrict__ ei,
    unsigned int* __restrict__ bins, int* __restrict__ bcur, char* smem)
{
  unsigned int* st = (unsigned int*)smem;
  int* h     = (int*)(smem + 16384);
  int* lofs  = (int*)(smem + 17168);
  int* gbase = (int*)(smem + 17952);
  int* buf   = (int*)(smem + 18736);
  const int tid = threadIdx.x;
  for (int i = tid; i < NBUCK; i += 256) h[i] = 0;
  __syncthreads();

  const int e0 = bid * E_PER_BLK;
  unsigned int pk[16];
  #pragma unroll
  for (int k = 0; k < 16; k++){
    int e = e0 + k*256 + tid;
    if (e < EP){
      int s, d;
      if (e < EE){ s = ei[e]; d = ei[EE + e]; } else { s = d = e - EE; }
      int b = d >> 8;
      pk[k] = ((unsigned)s << 16) | ((unsigned)b << 8) | (unsigned)(d & 255);
      atomicAdd(&h[b], 1);
    } else pk[k] = 0xFFFFFFFFu;      // sentinel
  }
  __syncthreads();

  int v = (tid < NBUCK) ? h[tid] : 0;
  buf[tid] = v;
  __syncthreads();
  for (int off = 1; off < 256; off <<= 1){
    int t = (tid >= off) ? buf[tid - off] : 0;
    __syncthreads();
    buf[tid] += t;
    __syncthreads();
  }
  if (tid < NBUCK){
    lofs[tid]  = buf[tid] - v;
    gbase[tid] = (v > 0) ? atomicAdd(&bcur[tid], v) : 0;
    h[tid] = lofs[tid];
  }
  __syncthreads();

  #pragma unroll
  for (int k = 0; k < 16; k++){
    if (pk[k] != 0xFFFFFFFFu){
      int b = (pk[k] >> 8) & 255;
      int p = atomicAdd(&h[b], 1);
      st[p] = pk[k];
    }
  }
  __syncthreads();

  const int total = buf[255];
  for (int i = tid; i < total; i += 256){
    unsigned int p = st[i];
    int b = (p >> 8) & 255;
    int idx = gbase[b] + (i - lofs[b]);
    if (idx < BCAP) bins[(size_t)b * BCAP + idx] = p;
  }
}

// pass 2: one block per bucket, 512 threads; emits rowStart + srcL + dstL.
__global__ void __launch_bounds__(512) binpass2_kernel(const unsigned int* __restrict__ bins,
    const int* __restrict__ bcur, int* __restrict__ rowStart,
    unsigned short* __restrict__ srcL, unsigned short* __restrict__ dstL)
{
  __shared__ int buf[256];
  __shared__ int lcnt[256];
  __shared__ int lcur[256];
  __shared__ int ebase_s, cnt_s;
  const int b = blockIdx.x;          // 0..195
  const int tid = threadIdx.x;

  int v = 0;
  if (tid < 256){
    v = (tid < NBUCK) ? bcur[tid] : 0;
    buf[tid] = v;
    lcnt[tid] = 0;
  }
  __syncthreads();
  for (int off = 1; off < 256; off <<= 1){
    int t = (tid >= off && tid < 256) ? buf[tid - off] : 0;
    __syncthreads();
    if (tid < 256) buf[tid] += t;
    __syncthreads();
  }
  if (tid == b){ ebase_s = buf[tid] - v; cnt_s = v; }
  __syncthreads();
  const int ebase = ebase_s, cnt = cnt_s;
  const unsigned int* mybins = bins + (size_t)b * BCAP;

  for (int i = tid; i < cnt; i += 512)
    atomicAdd(&lcnt[mybins[i] & 255], 1);
  __syncthreads();

  int c = 0;
  if (tid < 256){ c = lcnt[tid]; buf[tid] = c; }
  __syncthreads();
  for (int off = 1; off < 256; off <<= 1){
    int t = (tid >= off && tid < 256) ? buf[tid - off] : 0;
    __syncthreads();
    if (tid < 256) buf[tid] += t;
    __syncthreads();
  }
  if (tid < 256){
    int excl = buf[tid] - c;
    int d = (b << 8) + tid;
    if (d <= NN) rowStart[d] = ebase + excl;   // d==NN lands in bucket 195 -> EP
    lcur[tid] = ebase + excl;
  }
  __syncthreads();

  for (int i = tid; i < cnt; i += 512){
    unsigned int p = mybins[i];
    int dl = p & 255;
    int pos = atomicAdd(&lcur[dl], 1);
    srcL[pos] = (unsigned short)(p >> 16);
    dstL[pos] = (unsigned short)((b << 8) + dl);
  }
}

// ---------------- MFMA GEMM body ----------------
// XMODE 0: Xv = f32 raw input rows. XMODE 1: Xv = temp f32 (pre-bias); fused
// bias+LN+ELU prologue (R6-verified numerics). h stored SLICE-MAJOR
// Hout[(c*NN+row)*16+m] via LDS stage + coalesced stores; al node-major.
// Tail-specialized: only last block pays row guards.
template<int XMODE, int H>
__device__ __forceinline__ void gemm_body(int bid, const void* __restrict__ Xv,
    const float* __restrict__ lnb, const float* __restrict__ lng, const float* __restrict__ lnbe,
    const unsigned short* __restrict__ Wmf,
    unsigned short* __restrict__ Hout,
    float* __restrict__ alS, float* __restrict__ alD,
    unsigned short* wl)
{
  const int tid = threadIdx.x;
  {
    const uint4* src = (const uint4*)Wmf;
    uint4* dst = (uint4*)wl;
    #pragma unroll
    for (int i = 0; i < 9; i++)             // 9*256 = 2304 uint4 — full copy
      dst[tid + i*256] = src[tid + i*256];
  }
  const int lane = tid & 63, wv = tid >> 6;
  const int r0 = bid*64 + wv*16;
  const int m = lane & 15, quad = lane >> 4;
  const int row = r0 + m;
  const bool tail = (bid == GEMM_BLKS - 1);

  short8 a[4];
  if (XMODE == 0){
    const float* Xf = (const float*)Xv;
    #pragma unroll
    for (int kb = 0; kb < 4; kb++){
      if (!tail || row < NN){
        float4 f0 = *(const float4*)&Xf[(size_t)row*DD + kb*32 + quad*8];
        float4 f1 = *(const float4*)&Xf[(size_t)row*DD + kb*32 + quad*8 + 4];
        union { short8 v; unsigned short u[8]; } cv;
        cv.u[0]=f2bs(f0.x); cv.u[1]=f2bs(f0.y); cv.u[2]=f2bs(f0.z); cv.u[3]=f2bs(f0.w);
        cv.u[4]=f2bs(f1.x); cv.u[5]=f2bs(f1.y); cv.u[6]=f2bs(f1.z); cv.u[7]=f2bs(f1.w);
        a[kb] = cv.v;
      } else a[kb] = (short8){0,0,0,0,0,0,0,0};
    }
  } else {
    // fused bias + LN + ELU from temp (R6-verified)
    const float* T = (const float*)Xv;
    float xv[4][8];
    float s = 0.f, q = 0.f;
    #pragma unroll
    for (int kb = 0; kb < 4; kb++){
      int cb = kb*32 + quad*8;
      float4 f0 = make_float4(0.f,0.f,0.f,0.f), f1 = f0;
      if (!tail || row < NN){
        f0 = *(const float4*)&T[(size_t)row*DD + cb];
        f1 = *(const float4*)&T[(size_t)row*DD + cb + 4];
      }
      float4 b0_ = *(const float4*)&lnb[cb];
      float4 b1_ = *(const float4*)&lnb[cb + 4];
      xv[kb][0]=f0.x+b0_.x; xv[kb][1]=f0.y+b0_.y; xv[kb][2]=f0.z+b0_.z; xv[kb][3]=f0.w+b0_.w;
      xv[kb][4]=f1.x+b1_.x; xv[kb][5]=f1.y+b1_.y; xv[kb][6]=f1.z+b1_.z; xv[kb][7]=f1.w+b1_.w;
      #pragma unroll
      for (int j = 0; j < 8; j++){ s += xv[kb][j]; q += xv[kb][j]*xv[kb][j]; }
    }
    // reduce over the 4 lanes holding this row (lanes l, l^16, l^32, l^48)
    s += __shfl_xor(s, 16, 64); s += __shfl_xor(s, 32, 64);
    q += __shfl_xor(q, 16, 64); q += __shfl_xor(q, 32, 64);
    float mu  = s * (1.0f/128.0f);
    float var = q * (1.0f/128.0f) - mu*mu;
    float rr  = rsqrtf(var + 1e-5f);
    #pragma unroll
    for (int kb = 0; kb < 4; kb++){
      int cb = kb*32 + quad*8;
      float4 g0_ = *(const float4*)&lng[cb];
      float4 g1_ = *(const float4*)&lng[cb + 4];
      float4 e0_ = *(const float4*)&lnbe[cb];
      float4 e1_ = *(const float4*)&lnbe[cb + 4];
      float gg[8] = {g0_.x,g0_.y,g0_.z,g0_.w,g1_.x,g1_.y,g1_.z,g1_.w};
      float ee[8] = {e0_.x,e0_.y,e0_.z,e0_.w,e1_.x,e1_.y,e1_.z,e1_.w};
      union { short8 v; unsigned short u[8]; } cv;
      #pragma unroll
      for (int j = 0; j < 8; j++){
        float y = (xv[kb][j] - mu)*rr*gg[j] + ee[j];
        y = y > 0.f ? y : __expf(y) - 1.f;      // ELU (fused path is never final)
        cv.u[j] = f2bs(y);
      }
      a[kb] = cv.v;
    }
  }
  __syncthreads();

  f32x4 acc[9];
  #pragma unroll
  for (int c = 0; c < 9; c++) acc[c] = (f32x4){0.f,0.f,0.f,0.f};
  #pragma unroll
  for (int c = 0; c < 9; c++){
    #pragma unroll
    for (int kb = 0; kb < 4; kb++){
      short8 b = *(const short8*)&wl[((c*4 + kb)*64 + lane)*8];
      acc[c] = __builtin_amdgcn_mfma_f32_16x16x32_bf16(a[kb], b, acc[c], 0, 0, 0);
    }
  }

  // al store, node-major (register-only path, before LDS reuse)
  #pragma unroll
  for (int r = 0; r < 4; r++){
    int rw = r0 + quad*4 + r;
    if (!tail || rw < NN){
      float v = acc[8][r];
      if (H == 8){
        if (m < 8) alS[(size_t)rw*8 + m]       = v;
        else       alD[(size_t)rw*8 + (m - 8)] = v;
      } else {
        if (m == 0)      alS[rw] = v;
        else if (m == 1) alD[rw] = v;
      }
    }
  }

  // ---- h epilogue: LDS stage -> slice-major coalesced stores ----
  // D layout col=lane&15, row=quad*4+reg [m89/m91-verified]
  __syncthreads();                       // all wl B-frag reads complete
  unsigned short* ht = wl;               // 64 rows x 136 ushorts (272 B stride)
  const int lr = wv*16 + quad*4;
  #pragma unroll
  for (int c = 0; c < 8; c++){
    #pragma unroll
    for (int r = 0; r < 4; r++)
      ht[(lr + r)*136 + c*16 + m] = f2bs(acc[c][r]);
  }
  __syncthreads();
  const int r0b = bid*64;
  const int rw = tid >> 2, q4 = tid & 3;   // 64 rows x 4 chunks of 8B
  const int grow = r0b + rw;
  #pragma unroll
  for (int c = 0; c < 8; c++){
    if (!tail || grow < NN){
      uint2 v = *(const uint2*)&ht[rw*136 + c*16 + q4*4];
      *(uint2*)&Hout[((size_t)c*NN + grow)*16 + q4*4] = v;   // 2KB contiguous per c
    }
  }
}

// plain GEMM kernel (layers 1, 2: fused bias+LN+ELU input)
template<int XMODE, int H>
__global__ void __launch_bounds__(256) gemm_mfma_kernel(const void* __restrict__ Xv,
    const float* __restrict__ lnb, const float* __restrict__ lng, const float* __restrict__ lnbe,
    const unsigned short* __restrict__ Wmf,
    unsigned short* __restrict__ Hout,
    float* __restrict__ alS, float* __restrict__ alD)
{
  __shared__ unsigned short wl[36*64*8];    // 36 KB
  gemm_body<XMODE, H>(blockIdx.x, Xv, lnb, lng, lnbe, Wmf, Hout, alS, alD, wl);
}

// fused layer-0 kernel: bp1 blocks first (overlap), then gemm blocks.
__global__ void __launch_bounds__(256) gemm_bp1_kernel(const void* __restrict__ Xv,
    const unsigned short* __restrict__ Wmf,
    unsigned short* __restrict__ Hout,
    float* __restrict__ alS, float* __restrict__ alD,
    const int* __restrict__ ei, unsigned int* __restrict__ bins, int* __restrict__ bcur)
{
  __shared__ __align__(16) char smem[36*64*8*2];   // 36.9 KB union
  if (blockIdx.x < BP1_BLKS)
    bp1_body(blockIdx.x, ei, bins, bcur, smem);
  else
    gemm_body<0, 8>(blockIdx.x - BP1_BLKS, Xv, nullptr, nullptr, nullptr,
                    Wmf, Hout, alS, alD, (unsigned short*)smem);
}

// ---------------- bucketagg: per (256-dst bucket, 16-ch slice) softmax-aggregate ----------
// blk = bucket*8 + slice -> round-robin dispatch pins slice s to XCD s: each XCD's
// h working set is its own 1.6 MB slice (L2-resident, compulsory misses only).
// Contiguous CSR bucket: ~4350 edges streamed linearly, fixed overhead amortized
// 250x vs the R6 per-wave version (its failure mode).
template<int H>
__global__ void __launch_bounds__(256) bucketagg_kernel(
    const int* __restrict__ rowStart,
    const unsigned short* __restrict__ srcL, const unsigned short* __restrict__ dstL,
    const float* __restrict__ alS, const float* __restrict__ alD,
    const unsigned short* __restrict__ hB,     // slice-major [(sc*NN + node)*16 + ch]
    float* __restrict__ temp)                  // [node][128] f32 (normalized)
{
  __shared__ float wlds[BCAP];       // 32 KB edge weights
  __shared__ float accb[256*16];     // 16 KB per-dst/ch accumulators
  __shared__ float ssinv[256];       // 1 KB
  const int tid = threadIdx.x;
  const int blk = blockIdx.x;
  const int b = blk >> 3, sc = blk & 7;
  const int d0 = b << 8;
  const int ebase = rowStart[d0];
  const int eend  = rowStart[min(d0 + 256, NN)];
  const int cnt   = min(eend - ebase, BCAP);

  const unsigned short* __restrict__ hS = hB + (size_t)sc*NN*16;

  // phase 1: per-edge weight for THIS slice's head (1 exp/edge/slice) + zero acc
  for (int i = tid; i < cnt; i += 256){
    int e = ebase + i;
    int s = (int)srcL[e];
    int dl = dstL[e] & 255;
    float x;
    if (H == 8) x = alS[(size_t)s*8 + sc] + alD[(size_t)(d0 + dl)*8 + sc];
    else        x = alS[s] + alD[d0 + dl];
    x = fmaxf(x, 0.2f*x);              // leaky ReLU
    wlds[i] = __expf(x);
  }
  #pragma unroll
  for (int p = 0; p < 16; p++) accb[p*256 + tid] = 0.f;
  __syncthreads();

  // phase 2: per-dst inverse softmax sums (thread = local dst)
  {
    int d = d0 + tid;
    if (d < NN){
      int s0 = rowStart[d] - ebase;
      int s1 = min(rowStart[d+1] - ebase, BCAP);
      float s = 0.f;
      for (int i = s0; i < s1; ++i) s += wlds[i];
      ssinv[tid] = 1.f / s;
    }
  }

  // phase 3: gather-aggregate. 16 edge-groups x 16 ch; run-accumulate per dst
  // segment in registers (dl uniform within eg), flush via LDS float atomics.
  {
    const int eg = tid >> 4, ch = tid & 15;
    const int c0 = (cnt*eg) >> 4, c1 = (cnt*(eg+1)) >> 4;
    float racc = 0.f; int rundl = -1;
    int e = c0;
    for (; e + 8 <= c1; e += 8){
      int src[8], dl[8]; float hv[8], wv[8];
      #pragma unroll
      for (int j = 0; j < 8; j++){
        src[j] = (int)srcL[ebase + e + j];
        dl[j]  = dstL[ebase + e + j] & 255;
      }
      #pragma unroll
      for (int j = 0; j < 8; j++) hv[j] = bfu(hS[(size_t)src[j]*16 + ch]);
      #pragma unroll
      for (int j = 0; j < 8; j++) wv[j] = wlds[e + j];
      #pragma unroll
      for (int j = 0; j < 8; j++){
        if (dl[j] != rundl){
          if (rundl >= 0) atomicAdd(&accb[rundl*16 + ch], racc);
          rundl = dl[j]; racc = hv[j]*wv[j];
        } else racc = fmaf(hv[j], wv[j], racc);
      }
    }
    for (; e < c1; ++e){
      int src = (int)srcL[ebase + e];
      int dl  = dstL[ebase + e] & 255;
      float hv = bfu(hS[(size_t)src*16 + ch]);
      float wv = wlds[e];
      if (dl != rundl){
        if (rundl >= 0) atomicAdd(&accb[rundl*16 + ch], racc);
        rundl = dl; racc = hv*wv;
      } else racc = fmaf(hv, wv, racc);
    }
    if (rundl >= 0) atomicAdd(&accb[rundl*16 + ch], racc);
  }
  __syncthreads();

  // phase 4: normalize -> temp
  #pragma unroll
  for (int p = 0; p < 16; p++){
    int idx = p*256 + tid;
    int dl = idx >> 4, c = idx & 15;
    int d = d0 + dl;
    if (d < NN)
      temp[(size_t)d*DD + sc*16 + c] = accb[idx] * ssinv[dl];
  }
}

// ---------------- final finish: bias + LayerNorm over 128 ch -> f32 out ----------------
__global__ void __launch_bounds__(256) aggfin_kernel(
    const float* __restrict__ temp,
    const float* __restrict__ b, const float* __restrict__ g, const float* __restrict__ be,
    float* __restrict__ outv)
{
  const int lane = threadIdx.x & 63;
  const int d    = blockIdx.x*4 + (threadIdx.x >> 6);
  const int c0   = lane*2;

  float2 t = *(const float2*)&temp[(size_t)d*DD + c0];
  float v0 = t.x + b[c0], v1 = t.y + b[c0+1];
  float s2 = v0 + v1;
  #pragma unroll
  for (int off = 32; off >= 1; off >>= 1) s2 += __shfl_xor(s2, off, 64);
  float mu = s2 * (1.0f/128.0f);
  float d0 = v0 - mu, d1 = v1 - mu;
  float q = d0*d0 + d1*d1;
  #pragma unroll
  for (int off = 32; off >= 1; off >>= 1) q += __shfl_xor(q, off, 64);
  float r = rsqrtf(q*(1.0f/128.0f) + 1e-5f);
  float y0 = d0*r*g[c0]   + be[c0];
  float y1 = d1*r*g[c0+1] + be[c0+1];
  *(float2*)&outv[(size_t)d*DD + c0] = make_float2(y0, y1);
}

extern "C" void kernel_launch(void* const* d_in, const int* in_sizes, int n_in,
                              void* d_out, int out_size, void* d_ws, size_t ws_size,
                              hipStream_t stream)
{
  // ws layout (~45 MB)
  char* w = (char*)d_ws;
  unsigned short* hB   = (unsigned short*)w;     w += (size_t)NN*DD*2;    // 12.8 MB (slice-major)
  float* alS      = (float*)w;                   w += (size_t)NN*8*4;     // 1.6 MB (node-major)
  float* alD      = (float*)w;                   w += (size_t)NN*8*4;     // 1.6 MB
  float* temp     = (float*)w;                   w += (size_t)NN*DD*4;    // 25.6 MB
  unsigned short* Wmf = (unsigned short*)w;      w += (size_t)3*36*64*8*2;// 216 KB
  int*   rowStart = (int*)w;                     w += (size_t)(NN+1)*4;   // 200 KB
  int*   bcur     = (int*)w;                     w += 1024;
  unsigned short* srcL = (unsigned short*)w;     w += (size_t)EP*2;       // 1.7 MB
  unsigned short* dstL = (unsigned short*)w;     w += (size_t)EP*2;       // 1.7 MB
  if (ws_size < (size_t)(w - (char*)d_ws)) return;

  // bins (196*8192*4 = 6.4 MB) aliases temp: consumed (bp2) before bucketagg writes temp
  unsigned int* bins = (unsigned int*)temp;

  const float* x  = (const float*)d_in[0];
  const int*   ei = (const int*)d_in[1];
  const float *W0=(const float*)d_in[2], *as0=(const float*)d_in[3], *ad0=(const float*)d_in[4];
  const float *b0=(const float*)d_in[5], *g0=(const float*)d_in[6], *be0=(const float*)d_in[7];
  const float *W1=(const float*)d_in[8], *as1=(const float*)d_in[9], *ad1=(const float*)d_in[10];
  const float *b1=(const float*)d_in[11],*g1=(const float*)d_in[12],*be1=(const float*)d_in[13];
  const float *W2=(const float*)d_in[14],*as2=(const float*)d_in[15],*ad2=(const float*)d_in[16];
  const float *b2=(const float*)d_in[17],*g2=(const float*)d_in[18],*be2=(const float*)d_in[19];

  prep_kernel<<<NB, 256, 0, stream>>>(W0, as0, ad0, W1, as1, ad1, W2, as2, ad2, Wmf, bcur);

  // layer-0 GEMM fused with binpass1 (bp1 blocks first -> full overlap)
  gemm_bp1_kernel<<<GEMM_BLKS + BP1_BLKS, 256, 0, stream>>>(
      x, Wmf, hB, alS, alD, ei, bins, bcur);
  binpass2_kernel<<<NBUCK, 512, 0, stream>>>(bins, bcur, rowStart, srcL, dstL);

  // layer 0 aggregation (XCD-sliced, bucket-amortized)
  bucketagg_kernel<8><<<NBUCK*8, 256, 0, stream>>>(rowStart, srcL, dstL, alS, alD, hB, temp);

  // layer 1: GEMM with fused bias+LN+ELU input (b0/g0/be0), 8 heads
  gemm_mfma_kernel<1, 8><<<GEMM_BLKS, 256, 0, stream>>>(temp, b0, g0, be0,
      Wmf + (size_t)36*64*8, hB, alS, alD);
  bucketagg_kernel<8><<<NBUCK*8, 256, 0, stream>>>(rowStart, srcL, dstL, alS, alD, hB, temp);

  // layer 2: GEMM with fused bias+LN+ELU input (b1/g1/be1), 1 head
  gemm_mfma_kernel<1, 1><<<GEMM_BLKS, 256, 0, stream>>>(temp, b1, g1, be1,
      Wmf + (size_t)2*36*64*8, hB, alS, alD);
  bucketagg_kernel<1><<<NBUCK*8, 256, 0, stream>>>(rowStart, srcL, dstL, alS, alD, hB, temp);

  // final: bias + LN -> f32 out
  aggfin_kernel<<<12500, 256, 0, stream>>>(temp, b2, g2, be2, (float*)d_out);
}

// Round 11
// 271.316 us; speedup vs baseline: 2.2787x; 2.2787x over previous
//
#include <hip/hip_runtime.h>
#include <hip/hip_bf16.h>

#define NN 50000
#define EE 800000
#define EP 850000   // EE + NN self-loops
#define DD 128
#define NB 196      // ceil(NN/256)

#define NBUCK 196        // dst buckets: b = d >> 8 (d_max 49999 -> 195)
#define BCAP 8192        // slots per bucket (mean ~4350, 1.9x headroom)
#define E_PER_BLK 4096   // edges per binpass1 block (16/thread)
#define GEMM_BLKS 782    // ceil(NN/64)
#define BP1_BLKS ((EP + E_PER_BLK - 1)/E_PER_BLK)   // 208

typedef __attribute__((ext_vector_type(8))) short short8;
typedef __attribute__((ext_vector_type(4))) float f32x4;

__device__ __forceinline__ float bfu(unsigned short u){ return __uint_as_float(((unsigned)u)<<16); }
__device__ __forceinline__ unsigned short f2bs(float x){
  __hip_bfloat16 h = __float2bfloat16(x);
  union { __hip_bfloat16 h; unsigned short u; } cv; cv.h = h; return cv.u;
}

// ---------------- prep: zero bucket cursors (block 0) + pack W tiles (blocks 0..23)
// ---------------- + W@a fragments (blocks 24..119) --------------------------
__global__ void __launch_bounds__(256) prep_kernel(
    const float* __restrict__ W0, const float* __restrict__ as0, const float* __restrict__ ad0,
    const float* __restrict__ W1, const float* __restrict__ as1, const float* __restrict__ ad1,
    const float* __restrict__ W2, const float* __restrict__ as2, const float* __restrict__ ad2,
    unsigned short* __restrict__ Wmf, int* __restrict__ bcur)
{
  const int tid = threadIdx.x;
  if (blockIdx.x == 0 && tid < NBUCK) bcur[tid] = 0;
  if (blockIdx.x < 24){
    // W reformat, tiles 0..31
    const int L = blockIdx.x >> 3, seg = blockIdx.x & 7;
    const float* W = (L == 0) ? W0 : (L == 1) ? W1 : W2;
    int idx = seg*256 + tid;                  // 0..2047
    int t = idx >> 6, lane = idx & 63;        // t 0..31
    int c = t >> 2, kb = t & 3;
    int m = lane & 15, quad = lane >> 4;
    unsigned short out[8];
    #pragma unroll
    for (int j = 0; j < 8; j++){
      int k = kb*32 + quad*8 + j;
      out[j] = f2bs(W[(size_t)k*DD + c*16 + m]);
    }
    *(uint4*)&Wmf[(((size_t)L*36 + t)*64 + lane)*8] = *(const uint4*)out;
  } else if (blockIdx.x < 120){
    // W@a_src / W@a_dst -> tile 8; one wave per (layer,k)
    const int q = blockIdx.x - 24;
    const int wIdx = q*4 + (tid >> 6);        // 0..383
    const int L = wIdx >> 7, k = wIdx & 127;
    const float *W, *as, *ad; int H;
    if (L == 0){ W = W0; as = as0; ad = ad0; H = 8; }
    else if (L == 1){ W = W1; as = as1; ad = ad1; H = 8; }
    else { W = W2; as = as2; ad = ad2; H = 1; }
    const int lane = tid & 63;
    const int c0 = lane*2;
    float w0 = W[(size_t)k*DD + c0];
    float w1 = W[(size_t)k*DD + c0 + 1];
    float ps = w0*as[c0] + w1*as[c0+1];
    float pd = w0*ad[c0] + w1*ad[c0+1];
    if (H == 8){
      #pragma unroll
      for (int off = 1; off <= 4; off <<= 1){   // reduce within 8-lane head groups
        ps += __shfl_xor(ps, off, 64);
        pd += __shfl_xor(pd, off, 64);
      }
    } else {
      #pragma unroll
      for (int off = 1; off <= 32; off <<= 1){  // full-wave reduce
        ps += __shfl_xor(ps, off, 64);
        pd += __shfl_xor(pd, off, 64);
      }
    }
    int srcLane = (lane < 8) ? lane*8 : (lane < 16 ? (lane-8)*8 : 0);
    float vs = __shfl(ps, srcLane, 64);
    float vd = __shfl(pd, srcLane, 64);
    float myv;
    if (H == 8) myv = (lane < 8) ? vs : (lane < 16 ? vd : 0.f);
    else        myv = (lane == 0) ? ps : (lane == 1 ? pd : 0.f);
    const int kb = k >> 5, quad = (k >> 3) & 3, j = k & 7;
    if (lane < 16)
      Wmf[(((size_t)L*36 + 32 + kb)*64 + quad*16 + lane)*8 + j] = f2bs(myv);
  }
}

// ---------------- binpass1 body (called from fused layer-0 kernel) ----------------
// smem layout (19.8 KB of the 36.9 KB union)
__device__ __forceinline__ void bp1_body(int bid, const int* __restrict__ ei,
    unsigned int* __restrict__ bins, int* __restrict__ bcur, char* smem)
{
  unsigned int* st = (unsigned int*)smem;
  int* h     = (int*)(smem + 16384);
  int* lofs  = (int*)(smem + 17168);
  int* gbase = (int*)(smem + 17952);
  int* buf   = (int*)(smem + 18736);
  const int tid = threadIdx.x;
  for (int i = tid; i < NBUCK; i += 256) h[i] = 0;
  __syncthreads();

  const int e0 = bid * E_PER_BLK;
  unsigned int pk[16];
  #pragma unroll
  for (int k = 0; k < 16; k++){
    int e = e0 + k*256 + tid;
    if (e < EP){
      int s, d;
      if (e < EE){ s = ei[e]; d = ei[EE + e]; } else { s = d = e - EE; }
      int b = d >> 8;
      pk[k] = ((unsigned)s << 16) | ((unsigned)b << 8) | (unsigned)(d & 255);
      atomicAdd(&h[b], 1);
    } else pk[k] = 0xFFFFFFFFu;      // sentinel: s=65535 impossible (s<50000)
  }
  __syncthreads();

  // exclusive scan of h over 256 lanes; reserve global space per bucket
  int v = (tid < NBUCK) ? h[tid] : 0;
  buf[tid] = v;
  __syncthreads();
  for (int off = 1; off < 256; off <<= 1){
    int t = (tid >= off) ? buf[tid - off] : 0;
    __syncthreads();
    buf[tid] += t;
    __syncthreads();
  }
  if (tid < NBUCK){
    lofs[tid]  = buf[tid] - v;
    gbase[tid] = (v > 0) ? atomicAdd(&bcur[tid], v) : 0;
    h[tid] = lofs[tid];              // reuse h as LDS placement cursor
  }
  __syncthreads();

  // place into LDS staging grouped by bucket
  #pragma unroll
  for (int k = 0; k < 16; k++){
    if (pk[k] != 0xFFFFFFFFu){
      int b = (pk[k] >> 8) & 255;
      int p = atomicAdd(&h[b], 1);
      st[p] = pk[k];
    }
  }
  __syncthreads();

  // flush: contiguous per-bucket runs -> bins[b*BCAP + gbase[b] + local]
  const int total = buf[255];
  for (int i = tid; i < total; i += 256){
    unsigned int p = st[i];
    int b = (p >> 8) & 255;
    int idx = gbase[b] + (i - lofs[b]);
    if (idx < BCAP) bins[(size_t)b * BCAP + idx] = p;
  }
}

// pass 2: one block per bucket, 512 threads: hist+scatter at 2x throughput;
// 256-wide scans guarded to first 256 lanes.
__global__ void __launch_bounds__(512) binpass2_kernel(const unsigned int* __restrict__ bins,
    const int* __restrict__ bcur, int* __restrict__ rowStart, unsigned short* __restrict__ srcL)
{
  __shared__ int buf[256];
  __shared__ int lcnt[256];
  __shared__ int lcur[256];
  __shared__ int ebase_s, cnt_s;
  const int b = blockIdx.x;          // 0..195
  const int tid = threadIdx.x;

  int v = 0;
  if (tid < 256){
    v = (tid < NBUCK) ? bcur[tid] : 0;
    buf[tid] = v;
    lcnt[tid] = 0;
  }
  __syncthreads();
  for (int off = 1; off < 256; off <<= 1){
    int t = (tid >= off && tid < 256) ? buf[tid - off] : 0;
    __syncthreads();
    if (tid < 256) buf[tid] += t;
    __syncthreads();
  }
  if (tid == b){ ebase_s = buf[tid] - v; cnt_s = v; }
  __syncthreads();
  const int ebase = ebase_s, cnt = cnt_s;
  const unsigned int* mybins = bins + (size_t)b * BCAP;

  // phase A: histogram by local dst (512-thread stride)
  for (int i = tid; i < cnt; i += 512)
    atomicAdd(&lcnt[mybins[i] & 255], 1);
  __syncthreads();

  // phase B: exclusive scan -> rowStart (coalesced) + init cursors
  int c = 0;
  if (tid < 256){ c = lcnt[tid]; buf[tid] = c; }
  __syncthreads();
  for (int off = 1; off < 256; off <<= 1){
    int t = (tid >= off && tid < 256) ? buf[tid - off] : 0;
    __syncthreads();
    if (tid < 256) buf[tid] += t;
    __syncthreads();
  }
  if (tid < 256){
    int excl = buf[tid] - c;
    int d = (b << 8) + tid;
    if (d <= NN) rowStart[d] = ebase + excl;   // d==NN lands in bucket 195 -> EP
    lcur[tid] = ebase + excl;
  }
  __syncthreads();

  // phase C: scatter into this bucket's srcL window (512-thread stride)
  for (int i = tid; i < cnt; i += 512){
    unsigned int p = mybins[i];
    int pos = atomicAdd(&lcur[p & 255], 1);
    srcL[pos] = (unsigned short)(p >> 16);
  }
}

// ---------------- MFMA GEMM body: h = x@W (bf16 out) + al dots via 9th col tile --------
// R8: coalesced h-epilogue via LDS transpose-stage (272B padded stride).
// R9: tail-specialized — only the last block pays row guards.
template<bool XBF16, int H>
__device__ __forceinline__ void gemm_body(int bid, const void* __restrict__ Xv,
    const unsigned short* __restrict__ Wmf,
    unsigned short* __restrict__ Hout,
    float* __restrict__ alS, float* __restrict__ alD,
    unsigned short* wl)
{
  const int tid = threadIdx.x;
  {
    const uint4* src = (const uint4*)Wmf;
    uint4* dst = (uint4*)wl;
    #pragma unroll
    for (int i = 0; i < 9; i++)             // 9*256 = 2304 uint4 — full copy
      dst[tid + i*256] = src[tid + i*256];
  }
  const int lane = tid & 63, wv = tid >> 6;
  const int r0 = bid*64 + wv*16;
  const int m = lane & 15, quad = lane >> 4;
  const int row = r0 + m;
  const bool tail = (bid == GEMM_BLKS - 1);   // rows 49984..50047: only block needing guards

  short8 a[4];
  if (XBF16){
    const short* Xb = (const short*)Xv;
    if (!tail){
      #pragma unroll
      for (int kb = 0; kb < 4; kb++)
        a[kb] = *(const short8*)&Xb[(size_t)row*DD + kb*32 + quad*8];
    } else {
      #pragma unroll
      for (int kb = 0; kb < 4; kb++){
        if (row < NN) a[kb] = *(const short8*)&Xb[(size_t)row*DD + kb*32 + quad*8];
        else          a[kb] = (short8){0,0,0,0,0,0,0,0};
      }
    }
  } else {
    const float* Xf = (const float*)Xv;
    #pragma unroll
    for (int kb = 0; kb < 4; kb++){
      if (!tail || row < NN){
        float4 f0 = *(const float4*)&Xf[(size_t)row*DD + kb*32 + quad*8];
        float4 f1 = *(const float4*)&Xf[(size_t)row*DD + kb*32 + quad*8 + 4];
        union { short8 v; unsigned short u[8]; } cv;
        cv.u[0]=f2bs(f0.x); cv.u[1]=f2bs(f0.y); cv.u[2]=f2bs(f0.z); cv.u[3]=f2bs(f0.w);
        cv.u[4]=f2bs(f1.x); cv.u[5]=f2bs(f1.y); cv.u[6]=f2bs(f1.z); cv.u[7]=f2bs(f1.w);
        a[kb] = cv.v;
      } else a[kb] = (short8){0,0,0,0,0,0,0,0};
    }
  }
  __syncthreads();

  f32x4 acc[9];
  #pragma unroll
  for (int c = 0; c < 9; c++) acc[c] = (f32x4){0.f,0.f,0.f,0.f};
  #pragma unroll
  for (int c = 0; c < 9; c++){
    #pragma unroll
    for (int kb = 0; kb < 4; kb++){
      short8 b = *(const short8*)&wl[((c*4 + kb)*64 + lane)*8];
      acc[c] = __builtin_amdgcn_mfma_f32_16x16x32_bf16(a[kb], b, acc[c], 0, 0, 0);
    }
  }

  // al store from tile 8 (register-only path, before LDS reuse)
  if (!tail){
    #pragma unroll
    for (int r = 0; r < 4; r++){
      int rw = r0 + quad*4 + r;
      float v = acc[8][r];
      if (H == 8){
        if (m < 8) alS[rw*8 + m]       = v;
        else       alD[rw*8 + (m - 8)] = v;
      } else {
        if (m == 0)      alS[rw] = v;
        else if (m == 1) alD[rw] = v;
      }
    }
  } else {
    #pragma unroll
    for (int r = 0; r < 4; r++){
      int rw = r0 + quad*4 + r;
      if (rw < NN){
        float v = acc[8][r];
        if (H == 8){
          if (m < 8) alS[rw*8 + m]       = v;
          else       alD[rw*8 + (m - 8)] = v;
        } else {
          if (m == 0)      alS[rw] = v;
          else if (m == 1) alD[rw] = v;
        }
      }
    }
  }

  // ---- h epilogue: LDS transpose-stage -> coalesced stores ----
  // D layout col=lane&15, row=quad*4+reg [m89/m91-verified]
  __syncthreads();                       // all wl B-frag reads complete
  unsigned short* ht = wl;               // 64 rows x 136 ushorts (272 B stride)
  const int lr = wv*16 + quad*4;
  #pragma unroll
  for (int c = 0; c < 8; c++){
    #pragma unroll
    for (int r = 0; r < 4; r++)
      ht[(lr + r)*136 + c*16 + m] = f2bs(acc[c][r]);
  }
  __syncthreads();
  const int r0b = bid*64;
  if (!tail){
    #pragma unroll
    for (int p = 0; p < 4; p++){
      int i = p*256 + tid;
      int lrow = i >> 4, chunk = i & 15;   // 16 chunks x 16B = 256B row
      uint4 v = *(const uint4*)((const char*)ht + lrow*272 + chunk*16);
      *(uint4*)&Hout[(size_t)(r0b + lrow)*DD + chunk*8] = v;
    }
  } else {
    #pragma unroll
    for (int p = 0; p < 4; p++){
      int i = p*256 + tid;
      int lrow = i >> 4, chunk = i & 15;
      int grow = r0b + lrow;
      if (grow < NN){
        uint4 v = *(const uint4*)((const char*)ht + lrow*272 + chunk*16);
        *(uint4*)&Hout[(size_t)grow*DD + chunk*8] = v;
      }
    }
  }
}

// plain GEMM kernel (layers 1, 2)
template<bool XBF16, int H>
__global__ void __launch_bounds__(256) gemm_mfma_kernel(const void* __restrict__ Xv,
    const unsigned short* __restrict__ Wmf,
    unsigned short* __restrict__ Hout,
    float* __restrict__ alS, float* __restrict__ alD)
{
  __shared__ unsigned short wl[36*64*8];    // 36 KB
  gemm_body<XBF16, H>(blockIdx.x, Xv, Wmf, Hout, alS, alD, wl);
}

// fused layer-0 kernel: blocks [0,BP1_BLKS) run binpass1 (dispatched FIRST so the
// CSR build overlaps the GEMM instead of tailing it); rest run gemm.
template<bool XBF16, int H>
__global__ void __launch_bounds__(256) gemm_bp1_kernel(const void* __restrict__ Xv,
    const unsigned short* __restrict__ Wmf,
    unsigned short* __restrict__ Hout,
    float* __restrict__ alS, float* __restrict__ alD,
    const int* __restrict__ ei, unsigned int* __restrict__ bins, int* __restrict__ bcur)
{
  __shared__ __align__(16) char smem[36*64*8*2];   // 36.9 KB union
  if (blockIdx.x < BP1_BLKS)
    bp1_body(blockIdx.x, ei, bins, bcur, smem);
  else
    gemm_body<XBF16, H>(blockIdx.x - BP1_BLKS, Xv, Wmf, Hout, alS, alD,
                        (unsigned short*)smem);
}

// ---------------- fused: per-dst softmax + gather-aggregate + bias + LN (+ELU) ----------------
// R3-proven structure (at its L2-fill roofline): scalar edge metadata, SGPR row
// bases, ~9 VALU/edge. one wave per dst node; lane covers channels 2*lane, 2*lane+1.
template<int H, bool FINAL>
__global__ void __launch_bounds__(256) aggln_kernel(
    const int* __restrict__ rowStart, const unsigned short* __restrict__ srcL,
    const float* __restrict__ alS, const float* __restrict__ alD,
    const unsigned short* __restrict__ hB,
    const float* __restrict__ b, const float* __restrict__ g, const float* __restrict__ be,
    void* __restrict__ outv)
{
  const int lane = threadIdx.x & 63;
  const int d    = blockIdx.x*4 + (threadIdx.x >> 6);
  const int C    = DD / H;
  const int c0   = lane*2;
  const int hd   = c0 / C;
  const int start = __builtin_amdgcn_readfirstlane(rowStart[d]);
  const int end   = __builtin_amdgcn_readfirstlane(rowStart[d+1]);
  const float aldv = alD[d*H + hd];

  float ssum = 0.f, a0 = 0.f, a1 = 0.f;
  const unsigned int* __restrict__ sw = (const unsigned int*)srcL;

  // per-edge body: s is wave-uniform (SGPR) -> row bases are SALU
  #define PROC(sv) { \
    int s_ = (sv); \
    const unsigned short* hr_ = hB + (size_t)s_*DD; \
    const float* ar_ = alS + s_*H; \
    unsigned int hw_ = *(const unsigned int*)&hr_[c0]; \
    float e_ = ar_[hd] + aldv; \
    e_ = fmaxf(e_, 0.2f*e_); \
    float w_ = __expf(e_); \
    ssum += w_; \
    a0 = fmaf(__uint_as_float(hw_ << 16),          w_, a0); \
    a1 = fmaf(__uint_as_float(hw_ & 0xFFFF0000u),  w_, a1); \
  }

  int jw = start >> 1;
  if (start & 1){                         // head: odd start -> hi half only
    unsigned int w = sw[jw]; PROC((int)(w >> 16)); jw++;
  }
  const int jwF = end >> 1;               // words with both edges valid
  for (; jw + 2 <= jwF; jw += 2){         // 4 edges per iteration
    unsigned int w0 = sw[jw], w1 = sw[jw+1];
    PROC((int)(w0 & 0xFFFFu)); PROC((int)(w0 >> 16));
    PROC((int)(w1 & 0xFFFFu)); PROC((int)(w1 >> 16));
  }
  for (; jw < jwF; ++jw){
    unsigned int w = sw[jw];
    PROC((int)(w & 0xFFFFu)); PROC((int)(w >> 16));
  }
  if (end & 1){                           // tail: odd end -> lo half only
    unsigned int w = sw[jwF]; PROC((int)(w & 0xFFFFu));
  }
  #undef PROC

  const float sinv = 1.f / ssum;

  // bias + LayerNorm across the wave's 128 channels
  float v0 = a0*sinv + b[c0], v1 = a1*sinv + b[c0+1];
  float s2 = v0 + v1;
  #pragma unroll
  for (int off = 32; off >= 1; off >>= 1) s2 += __shfl_xor(s2, off, 64);
  float mu = s2 * (1.0f/128.0f);
  float d0 = v0 - mu, d1 = v1 - mu;
  float q = d0*d0 + d1*d1;
  #pragma unroll
  for (int off = 32; off >= 1; off >>= 1) q += __shfl_xor(q, off, 64);
  float r = rsqrtf(q*(1.0f/128.0f) + 1e-5f);
  float y0 = d0*r*g[c0]   + be[c0];
  float y1 = d1*r*g[c0+1] + be[c0+1];
  if (FINAL){
    *(float2*)&((float*)outv)[(size_t)d*DD + c0] = make_float2(y0, y1);
  } else {
    y0 = y0 > 0.f ? y0 : __expf(y0) - 1.f;   // ELU
    y1 = y1 > 0.f ? y1 : __expf(y1) - 1.f;
    ushort2 o; o.x = f2bs(y0); o.y = f2bs(y1);
    *(ushort2*)&((unsigned short*)outv)[(size_t)d*DD + c0] = o;
  }
}

extern "C" void kernel_launch(void* const* d_in, const int* in_sizes, int n_in,
                              void* d_out, int out_size, void* d_ws, size_t ws_size,
                              hipStream_t stream)
{
  // ws layout (~31 MB)
  char* w = (char*)d_ws;
  unsigned short* accB = (unsigned short*)w;     w += (size_t)NN*DD*2;   // 12.8 MB (bf16 x-next)
  unsigned short* hB   = (unsigned short*)w;     w += (size_t)NN*DD*2;   // 12.8 MB (bf16 h)
  float* alS      = (float*)w;                   w += (size_t)NN*8*4;    // 1.6 MB
  float* alD      = (float*)w;                   w += (size_t)NN*8*4;    // 1.6 MB
  unsigned short* Wmf = (unsigned short*)w;      w += (size_t)3*36*64*8*2; // 216 KB
  int*   rowStart = (int*)w;                     w += (size_t)(NN+1)*4;  // 200 KB
  int*   bcur     = (int*)w;                     w += 1024;              // bucket counts/cursors
  unsigned short* srcL = (unsigned short*)w;     w += (size_t)EP*2;      // 1.7 MB
  if (ws_size < (size_t)(w - (char*)d_ws)) return;

  // bins (196*8192*4 = 6.4 MB) aliases accB: consumed before layer 0 writes accB
  unsigned int* bins = (unsigned int*)accB;

  const float* x  = (const float*)d_in[0];
  const int*   ei = (const int*)d_in[1];
  const float *W0=(const float*)d_in[2], *as0=(const float*)d_in[3], *ad0=(const float*)d_in[4];
  const float *b0=(const float*)d_in[5], *g0=(const float*)d_in[6], *be0=(const float*)d_in[7];
  const float *W1=(const float*)d_in[8], *as1=(const float*)d_in[9], *ad1=(const float*)d_in[10];
  const float *b1=(const float*)d_in[11],*g1=(const float*)d_in[12],*be1=(const float*)d_in[13];
  const float *W2=(const float*)d_in[14],*as2=(const float*)d_in[15],*ad2=(const float*)d_in[16];
  const float *b2=(const float*)d_in[17],*g2=(const float*)d_in[18],*be2=(const float*)d_in[19];

  prep_kernel<<<NB, 256, 0, stream>>>(W0, as0, ad0, W1, as1, ad1, W2, as2, ad2, Wmf, bcur);

  // layer-0 GEMM fused with binpass1 (bp1 blocks first -> full overlap)
  gemm_bp1_kernel<false, 8><<<GEMM_BLKS + BP1_BLKS, 256, 0, stream>>>(
      x, Wmf, hB, alS, alD, ei, bins, bcur);
  binpass2_kernel<<<NBUCK, 512, 0, stream>>>(bins, bcur, rowStart, srcL);

  // layer 0 aggregation: 8 heads, ELU -> accB (bf16)
  aggln_kernel<8, false><<<12500, 256, 0, stream>>>(rowStart, srcL, alS, alD, hB,
                                                    b0, g0, be0, accB);
  // layer 1: x = accB (bf16), 8 heads, ELU -> accB
  gemm_mfma_kernel<true, 8><<<GEMM_BLKS, 256, 0, stream>>>(accB, Wmf + (size_t)36*64*8,
                                                           hB, alS, alD);
  aggln_kernel<8, false><<<12500, 256, 0, stream>>>(rowStart, srcL, alS, alD, hB,
                                                    b1, g1, be1, accB);
  // layer 2: x = accB (bf16), 1 head, LN only -> d_out (f32)
  gemm_mfma_kernel<true, 1><<<GEMM_BLKS, 256, 0, stream>>>(accB, Wmf + (size_t)2*36*64*8,
                                                           hB, alS, alD);
  aggln_kernel<1, true><<<12500, 256, 0, stream>>>(rowStart, srcL, alS, alD, hB,
                                                   b2, g2, be2, d_out);
}